// Round 5
// baseline (179.807 us; speedup 1.0000x reference)
//
#include <hip/hip_runtime.h>

// NonLocalBlock, B=4, C=64, H=W=64, N=4096, Ch=32.  MFMA f16, fully-coalesced hot loop.
//
// Index algebra (verified rounds 1-4):
//  x1[b,i,k] = conv1_flat[b][i*32+k]   (raw reshape; conv1 [ch][hw] buffer IS x1 flat)
//  x2[b,k,j] = conv2 natural [k][j]
//  y3[b,j,c] = conv3_flat[b][j*32+c]
//  attn[b,i,j] = sum_k x1*x2 ; softmax over BATCH axis (4 elems, per (i,j))
//  O[b,i,c] = sum_j attn*y3 ;  y2[b,ch,hw] = O_flat[b][ch*4096+hw] -> conv4
//
// MFMA f16 16x16x32 (HW-verified r2-r4):
//  A: A[m=lane&15][k=(lane>>4)*8+e]   B: B[k=(lane>>4)*8+e][n=lane&15]
//  C/D: row=(lane>>4)*4+reg, col=lane&15;  A-frag of M == B-frag of M^T.
// Stage 1 computes S^T with PERMUTED X2 rows (tile jh row m' -> j=(m'>>2)*8+(m'&3)+jh*4)
// so lane (q,m) ends holding exactly P[i=m][k=q*8+e] = stage-2 B-frag. No transpose.
// NEW r5: X2f/Y3f are written by convs in fragment order -> attn loads are lane*16B
// contiguous. X1 carries a log2e factor so softmax uses raw exp2 (no max-sub; |s|<~35).
//
// X2f h8-index: ((b*128 + jt)*2 + jh)*64 + lane   (value: x2[b][k=q*8+e][jt*32+perm(m,jh)])
// Y3f h8-index: ((b*128 + jt)*2 + ch)*64 + lane   (value: y3[b][jt*32+q*8+e][ch*16+m])
//
// ws: X1h 1MB @0 | X2f 1MB @1M | Y3f 1MB @2M | OPh 8MB @3M (8 f16 slices)  = 11 MB

typedef _Float16 half8 __attribute__((ext_vector_type(8)));
typedef _Float16 half4 __attribute__((ext_vector_type(4)));
typedef float f32x4 __attribute__((ext_vector_type(4)));

#define N_PIX 4096
#define NB    4
#define JS    8
#define LOG2E 1.44269504088896f

// grid (128, 3): bx = b(2b)|chunk(4b)|oh(1b); 256 hw, o-half 16 per block; LDS weights.
__global__ __launch_bounds__(256) void convs_kernel(
    const float* __restrict__ x,
    const float* __restrict__ w1, const float* __restrict__ b1,
    const float* __restrict__ w2, const float* __restrict__ b2,
    const float* __restrict__ w3, const float* __restrict__ b3,
    _Float16* __restrict__ X1h, _Float16* __restrict__ X2f, _Float16* __restrict__ Y3f)
{
    const int t = blockIdx.y;
    const float* __restrict__ w  = (t == 0) ? w1 : ((t == 1) ? w2 : w3);
    const float* __restrict__ bb = (t == 0) ? b1 : ((t == 1) ? b2 : b3);

    __shared__ float sw[16][64];           // this block's o-half (4 KB)
    __shared__ float sbias[16];
    __shared__ _Float16 sbuf[8192];        // union: conv2 sX2 256x24 | conv3 sT 16x32x16

    const int tid   = threadIdx.x;
    const int b     = blockIdx.x >> 5;
    const int chunk = (blockIdx.x >> 1) & 15;
    const int oh    = blockIdx.x & 1;
    const int o0    = oh * 16;
    const int hw    = chunk * 256 + tid;

    for (int e = tid; e < 16 * 64; e += 256)
        sw[e >> 6][e & 63] = w[(o0 + (e >> 6)) * 64 + (e & 63)];
    if (tid < 16) sbias[tid] = bb[o0 + tid];
    __syncthreads();

    float xi[64];
    const float* xb = x + b * 64 * N_PIX + hw;
    #pragma unroll
    for (int c = 0; c < 64; c++) xi[c] = xb[c * N_PIX];

    float acc[16];
    #pragma unroll
    for (int oo = 0; oo < 16; oo++) {
        float a0 = sbias[oo], a1 = 0.f, a2 = 0.f, a3 = 0.f;
        #pragma unroll
        for (int c = 0; c < 64; c += 4) {
            a0 += xi[c + 0] * sw[oo][c + 0];
            a1 += xi[c + 1] * sw[oo][c + 1];
            a2 += xi[c + 2] * sw[oo][c + 2];
            a3 += xi[c + 3] * sw[oo][c + 3];
        }
        acc[oo] = (a0 + a1) + (a2 + a3);
    }

    if (t == 0) {
        // X1h flat [o][hw] (== x1 flat [i*32+k]); fold log2e for exp2 softmax
        #pragma unroll
        for (int oo = 0; oo < 16; oo++)
            X1h[b * 131072 + (o0 + oo) * N_PIX + hw] = (_Float16)(acc[oo] * LOG2E);
    } else if (t == 1) {
        // stage x2[k][j] half -> sX2[j_loc=tid][k_loc 0..15] (row stride 24 f16 = 48 B)
        #pragma unroll
        for (int oo = 0; oo < 16; oo++)
            sbuf[tid * 24 + oo] = (_Float16)acc[oo];
        __syncthreads();
        // write X2f fragments for q in {oh*2, oh*2+1}
        #pragma unroll
        for (int g = 0; g < 2; g++) {
            const int u    = g * 256 + tid;        // 0..511
            const int m    = u & 15;
            const int qh   = (u >> 4) & 1;
            const int jh   = (u >> 5) & 1;
            const int jt_l = (u >> 6) & 7;
            const int jl   = jt_l * 32 + ((m >> 2) * 8) + (m & 3) + jh * 4;
            half8 v = *(half8*)&sbuf[jl * 24 + qh * 8];
            const int q = oh * 2 + qh;
            *(half8*)&X2f[(((b * 128 + chunk * 8 + jt_l) * 2 + jh) * 64 + q * 16 + m) * 8] = v;
        }
    } else {
        // y3 element acc[oo]: j = (o0+oo)*128 + (hw>>5), c = hw&31.
        // sT[(o_loc*32 + c)*16 + jl], jl = tid>>5 (rows 32 B, b128-aligned)
        const int c  = tid & 31;
        const int jl = tid >> 5;
        #pragma unroll
        for (int oo = 0; oo < 16; oo++)
            sbuf[(oo * 32 + c) * 16 + jl] = (_Float16)acc[oo];
        __syncthreads();
        // Y3f fragment pieces: q = chunk&3, e = jl; full h8 per (o, ch, m)
        #pragma unroll
        for (int g = 0; g < 2; g++) {
            const int u    = g * 256 + tid;        // 0..511
            const int m    = u & 15;
            const int ch   = (u >> 4) & 1;
            const int o_l  = (u >> 5) & 15;
            half8 v = *(half8*)&sbuf[(o_l * 32 + ch * 16 + m) * 16];
            const int jt = (o0 + o_l) * 4 + (chunk >> 2);
            *(half8*)&Y3f[(((b * 128 + jt) * 2 + ch) * 64 + (chunk & 3) * 16 + m) * 8] = v;
        }
    }
}

// grid (128, 8): bx = i-pair (32 rows, il=0,1), by = js. Wave wv: 4 jt tiles.
__global__ __launch_bounds__(256) void attn_kernel(
    const _Float16* __restrict__ X1h, const _Float16* __restrict__ X2f,
    const _Float16* __restrict__ Y3f, _Float16* __restrict__ OPh)
{
    __shared__ float sRed[4 * 64 * 33];    // 33 KB, stride 33 = conflict-free

    const int tid  = threadIdx.x;
    const int wv   = tid >> 6;
    const int lane = tid & 63;
    const int m    = lane & 15;
    const int q    = lane >> 4;
    const int i0   = blockIdx.x * 32;
    const int js   = blockIdx.y;
    const int jt0  = js * 16 + wv * 4;     // global j-tile base for this wave

    // stage-1 B-frags (x1 A-frag data), both il tiles, all batches
    half8 bx1[NB][2];
    #pragma unroll
    for (int b = 0; b < NB; b++)
        #pragma unroll
        for (int il = 0; il < 2; il++)
            bx1[b][il] = *(const half8*)&X1h[b * 131072 + (i0 + il * 16 + m) * 32 + q * 8];

    f32x4 oaccT[NB][2][2];                 // [b][ch][il]
    #pragma unroll
    for (int b = 0; b < NB; b++)
        #pragma unroll
        for (int ch = 0; ch < 2; ch++)
            #pragma unroll
            for (int il = 0; il < 2; il++)
                oaccT[b][ch][il] = (f32x4){0.f, 0.f, 0.f, 0.f};

    for (int jt = 0; jt < 4; jt++) {
        const int jg = jt0 + jt;

        // fully-coalesced fragment loads: 16 x (lane*16B contiguous, 1 KB/wave)
        half8 ax2[NB][2], ay3[NB][2];
        #pragma unroll
        for (int b = 0; b < NB; b++) {
            #pragma unroll
            for (int jh = 0; jh < 2; jh++)
                ax2[b][jh] = *(const half8*)&X2f[(((b * 128 + jg) * 2 + jh) * 64 + lane) * 8];
            #pragma unroll
            for (int ch = 0; ch < 2; ch++)
                ay3[b][ch] = *(const half8*)&Y3f[(((b * 128 + jg) * 2 + ch) * 64 + lane) * 8];
        }

        #pragma unroll
        for (int il = 0; il < 2; il++) {
            // stage 1: S^T (logits pre-scaled by log2e)
            f32x4 sT[NB][2];
            #pragma unroll
            for (int b = 0; b < NB; b++)
                #pragma unroll
                for (int jh = 0; jh < 2; jh++)
                    sT[b][jh] = __builtin_amdgcn_mfma_f32_16x16x32_f16(
                        ax2[b][jh], bx1[b][il], (f32x4){0.f, 0.f, 0.f, 0.f}, 0, 0, 0);

            // batch-softmax via raw exp2 (safe: |s*log2e| < ~50), pack B-frag in-lane
            half8 pf[NB];
            #pragma unroll
            for (int jh = 0; jh < 2; jh++)
                #pragma unroll
                for (int r = 0; r < 4; r++) {
                    float e0 = exp2f(sT[0][jh][r]);
                    float e1 = exp2f(sT[1][jh][r]);
                    float e2 = exp2f(sT[2][jh][r]);
                    float e3 = exp2f(sT[3][jh][r]);
                    float rs = __builtin_amdgcn_rcpf(e0 + e1 + e2 + e3);
                    pf[0][jh * 4 + r] = (_Float16)(e0 * rs);
                    pf[1][jh * 4 + r] = (_Float16)(e1 * rs);
                    pf[2][jh * 4 + r] = (_Float16)(e2 * rs);
                    pf[3][jh * 4 + r] = (_Float16)(e3 * rs);
                }

            // stage 2: O^T += Y3^T x P^T
            #pragma unroll
            for (int b = 0; b < NB; b++)
                #pragma unroll
                for (int ch = 0; ch < 2; ch++)
                    oaccT[b][ch][il] = __builtin_amdgcn_mfma_f32_16x16x32_f16(
                        ay3[b][ch], pf[b], oaccT[b][ch][il], 0, 0, 0);
        }
    }

    // cross-wave reduction, two passes (one per il), then f16 partial store.
    const int bb = tid >> 6;
    const int lp = tid & 63;
    const int mm = lp & 15;
    const int qq = lp >> 4;
    for (int il = 0; il < 2; il++) {
        if (il) __syncthreads();
        #pragma unroll
        for (int b = 0; b < NB; b++)
            #pragma unroll
            for (int ch = 0; ch < 2; ch++)
                #pragma unroll
                for (int r = 0; r < 4; r++)
                    sRed[(wv * 64 + lane) * 33 + b * 8 + ch * 4 + r] = oaccT[b][ch][il][r];
        __syncthreads();
        #pragma unroll
        for (int ch = 0; ch < 2; ch++) {
            half4 v;
            #pragma unroll
            for (int r = 0; r < 4; r++) {
                const int f = bb * 8 + ch * 4 + r;
                v[r] = (_Float16)(sRed[(0 * 64 + lp) * 33 + f] + sRed[(1 * 64 + lp) * 33 + f]
                                + sRed[(2 * 64 + lp) * 33 + f] + sRed[(3 * 64 + lp) * 33 + f]);
            }
            *(half4*)&OPh[js * 524288 + (bb * 4096 + i0 + il * 16 + mm) * 32 + ch * 16 + qq * 4] = v;
        }
    }
}

// grid (128, 4): bx = b(2b)|chunk(5b of 128 hw); by*16 + (tid>>7)*8 = o-range (8 o / thread).
__global__ __launch_bounds__(256) void out_kernel(
    const _Float16* __restrict__ OPh, const float* __restrict__ w4,
    const float* __restrict__ b4, float* __restrict__ out)
{
    __shared__ float sw[16][32];           // this by's 16 o rows (2 KB)
    __shared__ float sbias[16];
    const int tid = threadIdx.x;
    const int ob  = blockIdx.y * 16;
    for (int e = tid; e < 16 * 32; e += 256)
        sw[e >> 5][e & 31] = w4[(ob + (e >> 5)) * 32 + (e & 31)];
    if (tid < 16) sbias[tid] = b4[ob + tid];
    __syncthreads();

    const int b    = blockIdx.x >> 5;
    const int hw   = (blockIdx.x & 31) * 128 + (tid & 127);
    const int og   = tid >> 7;             // 0/1 -> 8-o halves

    float y2[32];
    #pragma unroll
    for (int ch = 0; ch < 32; ch++) {
        float v = 0.f;
        #pragma unroll
        for (int p = 0; p < JS; p++)
            v += (float)OPh[p * 524288 + b * 131072 + ch * 4096 + hw];
        y2[ch] = v;
    }

    float* obp = out + b * 64 * N_PIX + hw;
    #pragma unroll
    for (int oo = 0; oo < 8; oo++) {
        const int ol = og * 8 + oo;
        float a0 = sbias[ol], a1 = 0.f, a2 = 0.f, a3 = 0.f;
        #pragma unroll
        for (int c = 0; c < 32; c += 4) {
            a0 += y2[c + 0] * sw[ol][c + 0];
            a1 += y2[c + 1] * sw[ol][c + 1];
            a2 += y2[c + 2] * sw[ol][c + 2];
            a3 += y2[c + 3] * sw[ol][c + 3];
        }
        obp[(ob + ol) * N_PIX] = (a0 + a1) + (a2 + a3);
    }
}

extern "C" void kernel_launch(void* const* d_in, const int* in_sizes, int n_in,
                              void* d_out, int out_size, void* d_ws, size_t ws_size,
                              hipStream_t stream) {
    const float* x  = (const float*)d_in[0];
    const float* w1 = (const float*)d_in[1];
    const float* b1 = (const float*)d_in[2];
    const float* w2 = (const float*)d_in[3];
    const float* b2 = (const float*)d_in[4];
    const float* w3 = (const float*)d_in[5];
    const float* b3 = (const float*)d_in[6];
    const float* w4 = (const float*)d_in[7];
    const float* b4 = (const float*)d_in[8];

    char* wsb = (char*)d_ws;
    _Float16* X1h = (_Float16*)(wsb);
    _Float16* X2f = (_Float16*)(wsb + (1 << 20));
    _Float16* Y3f = (_Float16*)(wsb + (2 << 20));
    _Float16* OPh = (_Float16*)(wsb + (3 << 20));   // JS x 1MB f16
    float*    out = (float*)d_out;

    dim3 g1(128, 3);
    convs_kernel<<<g1, 256, 0, stream>>>(x, w1, b1, w2, b2, w3, b3, X1h, X2f, Y3f);
    dim3 g2(128, JS);
    attn_kernel<<<g2, 256, 0, stream>>>(X1h, X2f, Y3f, OPh);
    dim3 g3(128, 4);
    out_kernel<<<g3, 256, 0, stream>>>(OPh, w4, b4, out);
}

// Round 6
// 122.442 us; speedup vs baseline: 1.4685x; 1.4685x over previous
//
#include <hip/hip_runtime.h>

// NonLocalBlock, B=4, C=64, H=W=64, N=4096, Ch=32.  MFMA f16, latency-tuned.
//
// Index algebra (verified rounds 1-5):
//  x1[b,i,k] = conv1_flat[b][i*32+k]   (raw reshape; conv1 [ch][hw] buffer IS x1 flat)
//  x2[b,k,j] = conv2 natural [k][j]
//  y3[b,j,c] = conv3_flat[b][j*32+c]
//  attn[b,i,j] = sum_k x1*x2 ; softmax over BATCH axis (4 elems, per (i,j))
//  O[b,i,c] = sum_j attn*y3 ;  y2[b,ch,hw] = O_flat[b][ch*4096+hw] -> conv4
//
// MFMA f16 16x16x32 (HW-verified r2-r5):
//  A: A[m=lane&15][k=(lane>>4)*8+e]   B: B[k=(lane>>4)*8+e][n=lane&15]
//  C/D: row=(lane>>4)*4+reg, col=lane&15;  A-frag of M == B-frag of M^T.
// Stage 1 computes S^T with PERMUTED X2 rows (tile jh row m' -> j=(m'>>2)*8+(m'&3)+jh*4)
// so lane (q,m) ends holding exactly P[i=m][k=q*8+e] = stage-2 B-frag. No transpose.
// X2f/Y3f are written by convs in fragment order -> attn loads are lane*16B contiguous:
//  X2f h8-index: ((b*128 + jt)*2 + jh)*64 + lane  (value: x2[b][k=q*8+e][jt*32+perm(m,jh)])
//  Y3f h8-index: ((b*128 + jt)*2 + ch)*64 + lane  (value: y3[b][jt*32+q*8+e][ch*16+m])
// X1 carries log2e so softmax is raw exp2 (|s*log2e| < ~50, safe in f32).
//
// ws: X1h 1MB @0 | X2f 1MB @1M | Y3f 1MB @2M | OPh 8MB @3M | O(f32) 4MB @11M = 15MB

typedef _Float16 half8 __attribute__((ext_vector_type(8)));
typedef _Float16 half4 __attribute__((ext_vector_type(4)));
typedef float f32x4 __attribute__((ext_vector_type(4)));

#define N_PIX 4096
#define NB    4
#define JS    8
#define LOG2E 1.44269504088896f

// grid (256, 3): bx = b(2b) | chunk(4b, 256 hw) | og(2b, 8 o).  LDS weights.
__global__ __launch_bounds__(256) void convs_kernel(
    const float* __restrict__ x,
    const float* __restrict__ w1, const float* __restrict__ b1,
    const float* __restrict__ w2, const float* __restrict__ b2,
    const float* __restrict__ w3, const float* __restrict__ b3,
    _Float16* __restrict__ X1h, _Float16* __restrict__ X2f, _Float16* __restrict__ Y3f)
{
    const int t = blockIdx.y;
    const float* __restrict__ w  = (t == 0) ? w1 : ((t == 1) ? w2 : w3);
    const float* __restrict__ bb = (t == 0) ? b1 : ((t == 1) ? b2 : b3);

    __shared__ float sw[8][64];            // this block's 8 o rows (2 KB)
    __shared__ float sbias[8];
    __shared__ _Float16 sbuf[2048];        // union: t1 [256 j][8 k] | t2 [8 o][32 c][8 jl]

    const int tid   = threadIdx.x;
    const int b     = blockIdx.x >> 6;
    const int chunk = (blockIdx.x >> 2) & 15;
    const int og    = blockIdx.x & 3;
    const int o0    = og * 8;
    const int hw    = chunk * 256 + tid;

    for (int e = tid; e < 8 * 64; e += 256)
        sw[e >> 6][e & 63] = w[(o0 + (e >> 6)) * 64 + (e & 63)];
    if (tid < 8) sbias[tid] = bb[o0 + tid];
    __syncthreads();

    float xi[64];
    const float* xb = x + b * 64 * N_PIX + hw;
    #pragma unroll
    for (int c = 0; c < 64; c++) xi[c] = xb[c * N_PIX];

    float acc[8];
    #pragma unroll
    for (int oo = 0; oo < 8; oo++) {
        float a0 = sbias[oo], a1 = 0.f, a2 = 0.f, a3 = 0.f;
        #pragma unroll
        for (int c = 0; c < 64; c += 4) {
            a0 += xi[c + 0] * sw[oo][c + 0];
            a1 += xi[c + 1] * sw[oo][c + 1];
            a2 += xi[c + 2] * sw[oo][c + 2];
            a3 += xi[c + 3] * sw[oo][c + 3];
        }
        acc[oo] = (a0 + a1) + (a2 + a3);
    }

    if (t == 0) {
        // X1h flat [o][hw] (== x1 flat [i*32+k]); fold log2e for exp2 softmax
        #pragma unroll
        for (int oo = 0; oo < 8; oo++)
            X1h[b * 131072 + (o0 + oo) * N_PIX + hw] = (_Float16)(acc[oo] * LOG2E);
    } else if (t == 1) {
        // block's k-range o0..o0+7 = exactly q=og octet of the frag; sbuf[j_loc][e]
        #pragma unroll
        for (int oo = 0; oo < 8; oo++)
            sbuf[tid * 8 + oo] = (_Float16)acc[oo];
        __syncthreads();
        const int m    = tid & 15;
        const int jh   = (tid >> 4) & 1;
        const int jt_l = (tid >> 5) & 7;                   // 8 j-tiles per 256 hw
        const int jl   = jt_l * 32 + ((m >> 2) * 8) + (m & 3) + jh * 4;  // perm row
        half8 v = *(half8*)&sbuf[jl * 8];
        *(half8*)&X2f[(((b * 128 + chunk * 8 + jt_l) * 2 + jh) * 64 + og * 16 + m) * 8] = v;
    } else {
        // y3 elem acc[oo]: o = o0+oo, j = o*128 + (hw>>5), c = hw&31.
        // j = (o0+oo)*128 + chunk*8 + jl  ->  jt = (o0+oo)*4 + (chunk>>2),
        // within-tile j&31 = (chunk&3)*8 + jl  ->  q = chunk&3, e = jl (full 0..7!).
        const int c  = tid & 31;
        const int jl = tid >> 5;                           // 0..7
        #pragma unroll
        for (int oo = 0; oo < 8; oo++)
            sbuf[(oo * 32 + c) * 8 + jl] = (_Float16)acc[oo];
        __syncthreads();
        const int m  = tid & 15;
        const int ch = (tid >> 4) & 1;
        const int oo = (tid >> 5) & 7;
        half8 v = *(half8*)&sbuf[(oo * 32 + ch * 16 + m) * 8];
        const int jt = (o0 + oo) * 4 + (chunk >> 2);
        *(half8*)&Y3f[(((b * 128 + jt) * 2 + ch) * 64 + (chunk & 3) * 16 + m) * 8] = v;
    }
}

// grid (256, 8): bx = i-tile (16 rows), by = js. Wave wv: 4 jt tiles (128 j).
__global__ __launch_bounds__(256) void attn_kernel(
    const _Float16* __restrict__ X1h, const _Float16* __restrict__ X2f,
    const _Float16* __restrict__ Y3f, _Float16* __restrict__ OPh)
{
    __shared__ _Float16 sRedH[4 * 64 * 36];  // 18.4 KB; stride 36 keeps half4 8B-aligned

    const int tid  = threadIdx.x;
    const int wv   = tid >> 6;
    const int lane = tid & 63;
    const int m    = lane & 15;
    const int q    = lane >> 4;
    const int i0   = blockIdx.x * 16;
    const int js   = blockIdx.y;
    const int jt0  = js * 16 + wv * 4;

    // stage-1 B-frags (x1 A-frag data), all batches (1 KB contiguous per wave-load)
    half8 bx1[NB];
    #pragma unroll
    for (int b = 0; b < NB; b++)
        bx1[b] = *(const half8*)&X1h[b * 131072 + (i0 + m) * 32 + q * 8];

    f32x4 oaccT[NB][2];                      // [b][ch], lane holds O^T[c][i]
    #pragma unroll
    for (int b = 0; b < NB; b++) {
        oaccT[b][0] = (f32x4){0.f, 0.f, 0.f, 0.f};
        oaccT[b][1] = (f32x4){0.f, 0.f, 0.f, 0.f};
    }

    for (int jt = 0; jt < 4; jt++) {
        const int jg = jt0 + jt;

        // fully-coalesced fragment loads (lane*16B contiguous, 1 KB per wave-inst)
        half8 ax2[NB][2], ay3[NB][2];
        #pragma unroll
        for (int b = 0; b < NB; b++) {
            #pragma unroll
            for (int jh = 0; jh < 2; jh++)
                ax2[b][jh] = *(const half8*)&X2f[(((b * 128 + jg) * 2 + jh) * 64 + lane) * 8];
            #pragma unroll
            for (int ch = 0; ch < 2; ch++)
                ay3[b][ch] = *(const half8*)&Y3f[(((b * 128 + jg) * 2 + ch) * 64 + lane) * 8];
        }

        // stage 1: S^T (logits pre-scaled by log2e)
        f32x4 sT[NB][2];
        #pragma unroll
        for (int b = 0; b < NB; b++)
            #pragma unroll
            for (int jh = 0; jh < 2; jh++)
                sT[b][jh] = __builtin_amdgcn_mfma_f32_16x16x32_f16(
                    ax2[b][jh], bx1[b], (f32x4){0.f, 0.f, 0.f, 0.f}, 0, 0, 0);

        // batch-softmax via raw exp2, pack stage-2 B-frag in-lane
        half8 pf[NB];
        #pragma unroll
        for (int jh = 0; jh < 2; jh++)
            #pragma unroll
            for (int r = 0; r < 4; r++) {
                float e0 = exp2f(sT[0][jh][r]);
                float e1 = exp2f(sT[1][jh][r]);
                float e2 = exp2f(sT[2][jh][r]);
                float e3 = exp2f(sT[3][jh][r]);
                float rs = __builtin_amdgcn_rcpf(e0 + e1 + e2 + e3);
                pf[0][jh * 4 + r] = (_Float16)(e0 * rs);
                pf[1][jh * 4 + r] = (_Float16)(e1 * rs);
                pf[2][jh * 4 + r] = (_Float16)(e2 * rs);
                pf[3][jh * 4 + r] = (_Float16)(e3 * rs);
            }

        // stage 2: O^T += Y3^T x P^T
        #pragma unroll
        for (int b = 0; b < NB; b++)
            #pragma unroll
            for (int ch = 0; ch < 2; ch++)
                oaccT[b][ch] = __builtin_amdgcn_mfma_f32_16x16x32_f16(
                    ay3[b][ch], pf[b], oaccT[b][ch], 0, 0, 0);
    }

    // cross-wave reduction in f16 LDS (values are attn-weighted partials, <=~1)
    #pragma unroll
    for (int b = 0; b < NB; b++)
        #pragma unroll
        for (int ch = 0; ch < 2; ch++) {
            half4 h;
            #pragma unroll
            for (int r = 0; r < 4; r++) h[r] = (_Float16)oaccT[b][ch][r];
            *(half4*)&sRedH[(wv * 64 + lane) * 36 + b * 8 + ch * 4] = h;
        }
    __syncthreads();

    const int bb = tid >> 6;                 // wave writes batch b=bb
    const int lp = tid & 63;
    const int mm = lp & 15;
    const int qq = lp >> 4;
    #pragma unroll
    for (int ch = 0; ch < 2; ch++) {
        half4 h0 = *(half4*)&sRedH[(0 * 64 + lp) * 36 + bb * 8 + ch * 4];
        half4 h1 = *(half4*)&sRedH[(1 * 64 + lp) * 36 + bb * 8 + ch * 4];
        half4 h2 = *(half4*)&sRedH[(2 * 64 + lp) * 36 + bb * 8 + ch * 4];
        half4 h3 = *(half4*)&sRedH[(3 * 64 + lp) * 36 + bb * 8 + ch * 4];
        half4 v;
        #pragma unroll
        for (int r = 0; r < 4; r++)
            v[r] = (_Float16)(((float)h0[r] + (float)h1[r]) + ((float)h2[r] + (float)h3[r]));
        *(half4*)&OPh[js * 524288 + (bb * 4096 + i0 + mm) * 32 + ch * 16 + qq * 4] = v;
    }
}

// grid 256: sum 8 f16 partial slices -> f32 O.  Pure BW: h8 loads, float4 stores.
__global__ __launch_bounds__(256) void reduce_kernel(
    const _Float16* __restrict__ OPh, float* __restrict__ O)
{
    const int u = blockIdx.x * 256 + threadIdx.x;    // 0..65535
    const int base = u * 8;
    float acc[8] = {};
    #pragma unroll
    for (int p = 0; p < JS; p++) {
        half8 v = *(const half8*)&OPh[p * 524288 + base];
        #pragma unroll
        for (int e = 0; e < 8; e++) acc[e] += (float)v[e];
    }
    *(f32x4*)&O[base]     = (f32x4){acc[0], acc[1], acc[2], acc[3]};
    *(f32x4*)&O[base + 4] = (f32x4){acc[4], acc[5], acc[6], acc[7]};
}

// grid (256, 4): bx = b(2b) | chunk(6b, 64 hw); by*16 + og*4 = o-range (4 o / thread).
// O flat index ch*4096+hw is exactly y2[b][ch][hw]; conv4 with coalesced f32 loads.
__global__ __launch_bounds__(256) void out_kernel(
    const float* __restrict__ O, const float* __restrict__ w4,
    const float* __restrict__ b4, float* __restrict__ out)
{
    __shared__ float sw[16][32];             // this by's 16 o rows (2 KB)
    __shared__ float sbias[16];
    const int tid = threadIdx.x;
    const int ob  = blockIdx.y * 16;
    for (int e = tid; e < 16 * 32; e += 256)
        sw[e >> 5][e & 31] = w4[(ob + (e >> 5)) * 32 + (e & 31)];
    if (tid < 16) sbias[tid] = b4[ob + tid];
    __syncthreads();

    const int b   = blockIdx.x >> 6;
    const int hw  = (blockIdx.x & 63) * 64 + (tid & 63);
    const int og  = tid >> 6;                // 0..3 -> 4-o quarters

    float y2[32];
    #pragma unroll
    for (int ch = 0; ch < 32; ch++)
        y2[ch] = O[b * 131072 + ch * 4096 + hw];       // 32 independent coalesced loads

    float* obp = out + b * 64 * N_PIX + hw;
    #pragma unroll
    for (int oo = 0; oo < 4; oo++) {
        const int ol = og * 4 + oo;
        float a0 = sbias[ol], a1 = 0.f, a2 = 0.f, a3 = 0.f;
        #pragma unroll
        for (int c = 0; c < 32; c += 4) {
            a0 += y2[c + 0] * sw[ol][c + 0];
            a1 += y2[c + 1] * sw[ol][c + 1];
            a2 += y2[c + 2] * sw[ol][c + 2];
            a3 += y2[c + 3] * sw[ol][c + 3];
        }
        obp[(ob + ol) * N_PIX] = (a0 + a1) + (a2 + a3);
    }
}

extern "C" void kernel_launch(void* const* d_in, const int* in_sizes, int n_in,
                              void* d_out, int out_size, void* d_ws, size_t ws_size,
                              hipStream_t stream) {
    const float* x  = (const float*)d_in[0];
    const float* w1 = (const float*)d_in[1];
    const float* b1 = (const float*)d_in[2];
    const float* w2 = (const float*)d_in[3];
    const float* b2 = (const float*)d_in[4];
    const float* w3 = (const float*)d_in[5];
    const float* b3 = (const float*)d_in[6];
    const float* w4 = (const float*)d_in[7];
    const float* b4 = (const float*)d_in[8];

    char* wsb = (char*)d_ws;
    _Float16* X1h = (_Float16*)(wsb);
    _Float16* X2f = (_Float16*)(wsb + (1 << 20));
    _Float16* Y3f = (_Float16*)(wsb + (2 << 20));
    _Float16* OPh = (_Float16*)(wsb + (3 << 20));    // JS x 1MB f16
    float*    O   = (float*)   (wsb + (11 << 20));   // 4MB f32
    float*    out = (float*)d_out;

    dim3 g1(256, 3);
    convs_kernel<<<g1, 256, 0, stream>>>(x, w1, b1, w2, b2, w3, b3, X1h, X2f, Y3f);
    dim3 g2(256, JS);
    attn_kernel<<<g2, 256, 0, stream>>>(X1h, X2f, Y3f, OPh);
    reduce_kernel<<<256, 256, 0, stream>>>(OPh, O);
    dim3 g4(256, 4);
    out_kernel<<<g4, 256, 0, stream>>>(O, w4, b4, out);
}